// Round 18
// baseline (167.037 us; speedup 1.0000x reference)
//
#include <hip/hip_runtime.h>
#include <hip/hip_bf16.h>

#define N 8192
#define D 256
#define NF 8192.0f

typedef __bf16 bf16x8 __attribute__((ext_vector_type(8)));
typedef float f32x4 __attribute__((ext_vector_type(4)));

static __device__ __forceinline__ unsigned short f2bf(float x) {
    union { float f; unsigned int u; } c; c.f = x;
    unsigned int r = (c.u + 0x7fffu + ((c.u >> 16) & 1u)) >> 16;
    return (unsigned short)r;
}
static __device__ __forceinline__ float bf2f(unsigned short u) {
    union { float f; unsigned int u; } c; c.u = ((unsigned int)u) << 16;
    return c.f;
}

// ---------- kernel 1: norms, exact fp32 diag, A-hat bf16 (row-major),
// Bt = B-hat^T bf16 [256][8192] via LDS transpose, vp[b][k] = per-block col-sums ----
__global__ __launch_bounds__(256) void conv_k(const float* __restrict__ o1,
                                              const float* __restrict__ o2,
                                              unsigned char* __restrict__ a_bf,
                                              unsigned char* __restrict__ bt,
                                              float* __restrict__ vp,
                                              float* __restrict__ diag) {
    __shared__ unsigned short tile[32][256];   // 16 KB: [j-local][k]
    const int w = threadIdx.x >> 6, lane = threadIdx.x & 63;
    const int r0 = blockIdx.x * 32;

    #pragma unroll
    for (int t = 0; t < 8; ++t) {
        const int jloc = w * 8 + t;
        const int r = r0 + jloc;
        float4 x1 = ((const float4*)(o1 + (size_t)r * D))[lane];
        float4 x2 = ((const float4*)(o2 + (size_t)r * D))[lane];
        float s1 = x1.x*x1.x + x1.y*x1.y + x1.z*x1.z + x1.w*x1.w;
        float s2 = x2.x*x2.x + x2.y*x2.y + x2.z*x2.z + x2.w*x2.w;
        float sd = x1.x*x2.x + x1.y*x2.y + x1.z*x2.z + x1.w*x2.w;
        #pragma unroll
        for (int m = 1; m < 64; m <<= 1) {
            s1 += __shfl_xor(s1, m);
            s2 += __shfl_xor(s2, m);
            sd += __shfl_xor(sd, m);
        }
        float i1 = 1.0f / sqrtf(s1);
        float i2 = 1.0f / sqrtf(s2);
        if (lane == 0) diag[r] = sd * i1 * i2;

        uint2 qa;
        qa.x = (unsigned int)f2bf(x1.x * i1) | ((unsigned int)f2bf(x1.y * i1) << 16);
        qa.y = (unsigned int)f2bf(x1.z * i1) | ((unsigned int)f2bf(x1.w * i1) << 16);
        *(uint2*)(a_bf + (size_t)r * 512 + lane * 8) = qa;

        uint2 qb;
        qb.x = (unsigned int)f2bf(x2.x * i2) | ((unsigned int)f2bf(x2.y * i2) << 16);
        qb.y = (unsigned int)f2bf(x2.z * i2) | ((unsigned int)f2bf(x2.w * i2) << 16);
        *(uint2*)&tile[jloc][lane * 4] = qb;
    }
    __syncthreads();

    // transpose out: thread t = k; write Bt[k][r0..r0+31] (64 B) + v partial
    const int t = threadIdx.x;
    float vs = 0.f;
    unsigned int pk[16];
    #pragma unroll
    for (int j = 0; j < 16; ++j) {
        unsigned short y0 = tile[2 * j][t];
        unsigned short y1 = tile[2 * j + 1][t];
        vs += bf2f(y0) + bf2f(y1);
        pk[j] = (unsigned int)y0 | ((unsigned int)y1 << 16);
    }
    uint4* dst = (uint4*)(bt + (size_t)t * (2 * N) + (size_t)r0 * 2);
    #pragma unroll
    for (int q = 0; q < 4; ++q) {
        uint4 u; u.x = pk[4*q]; u.y = pk[4*q+1]; u.z = pk[4*q+2]; u.w = pk[4*q+3];
        dst[q] = u;
    }
    vp[(size_t)blockIdx.x * 256 + t] = vs;   // coalesced across threads
}

// ---------- kernel 2: M (bf16, direct) + v-reduce.
// blocks 0-15: 64x64 tile of M = Bt x Bt^T, full K=8192; 8 waves = 2x2 spatial x 2 j-half,
// LDS-combine halves, write Mb bf16. block 16: v[k] = sum_b vp[b][k].
__global__ __launch_bounds__(512) void mker2(const unsigned char* __restrict__ bt,
                                             const float* __restrict__ vp,
                                             unsigned short* __restrict__ Mb,
                                             float* __restrict__ v) {
    if (blockIdx.x == 16) {
        const int k = threadIdx.x;
        if (k < 256) {
            float s = 0.f;
            for (int b = 0; b < 256; ++b) s += vp[(size_t)b * 256 + k];
            v[k] = s;
        }
        return;
    }
    __shared__ float comb[4][64][16];   // 16 KB
    const int tid = threadIdx.x, lane = tid & 63, wid = tid >> 6;
    const int l15 = lane & 15, lk = lane >> 4;
    const int jh = wid >> 2, wq = wid & 3, wr = wq >> 1, wc = wq & 1;
    const int tm = blockIdx.x >> 2, tn = blockIdx.x & 3;
    const int rA = tm * 64 + wr * 32, rB = tn * 64 + wc * 32;

    f32x4 acc[2][2];
    #pragma unroll
    for (int mr = 0; mr < 2; ++mr)
        #pragma unroll
        for (int nt = 0; nt < 2; ++nt)
            acc[mr][nt] = (f32x4){0.f, 0.f, 0.f, 0.f};

    #pragma unroll 4
    for (int st = 0; st < 128; ++st) {
        const size_t joff = (size_t)jh * 8192 + st * 64 + lk * 16;
        bf16x8 a0 = *(const bf16x8*)(bt + (size_t)(rA + l15) * (2 * N) + joff);
        bf16x8 a1 = *(const bf16x8*)(bt + (size_t)(rA + 16 + l15) * (2 * N) + joff);
        bf16x8 b0 = *(const bf16x8*)(bt + (size_t)(rB + l15) * (2 * N) + joff);
        bf16x8 b1 = *(const bf16x8*)(bt + (size_t)(rB + 16 + l15) * (2 * N) + joff);
        acc[0][0] = __builtin_amdgcn_mfma_f32_16x16x32_bf16(a0, b0, acc[0][0], 0, 0, 0);
        acc[0][1] = __builtin_amdgcn_mfma_f32_16x16x32_bf16(a0, b1, acc[0][1], 0, 0, 0);
        acc[1][0] = __builtin_amdgcn_mfma_f32_16x16x32_bf16(a1, b0, acc[1][0], 0, 0, 0);
        acc[1][1] = __builtin_amdgcn_mfma_f32_16x16x32_bf16(a1, b1, acc[1][1], 0, 0, 0);
    }

    if (jh == 1) {
        #pragma unroll
        for (int mr = 0; mr < 2; ++mr)
            #pragma unroll
            for (int nt = 0; nt < 2; ++nt)
                #pragma unroll
                for (int rg = 0; rg < 4; ++rg)
                    comb[wq][lane][(mr * 2 + nt) * 4 + rg] = acc[mr][nt][rg];
    }
    __syncthreads();
    if (jh == 0) {
        #pragma unroll
        for (int mr = 0; mr < 2; ++mr)
            #pragma unroll
            for (int nt = 0; nt < 2; ++nt)
                #pragma unroll
                for (int rg = 0; rg < 4; ++rg) {
                    float s = acc[mr][nt][rg] + comb[wq][lane][(mr * 2 + nt) * 4 + rg];
                    int row = rA + mr * 16 + lk * 4 + rg;
                    int col = rB + nt * 16 + l15;
                    Mb[row * D + col] = f2bf(s);
                }
    }
}

// ---------- kernel 3: fused quadratic forms + per-row loss + block reduce ----------
// grid 64; block 256 = 4 waves x 32 rows; full n (ne = 0..7 in-register).
__global__ __launch_bounds__(256) void qf2(const unsigned char* __restrict__ a_bf,
                                           const unsigned char* __restrict__ Mb,
                                           const float* __restrict__ v,
                                           const float* __restrict__ diag,
                                           float* __restrict__ partial) {
    const int tid = threadIdx.x, lane = tid & 63, wid = tid >> 6;
    const int l15 = lane & 15, lk = lane >> 4;
    const int rowbase = blockIdx.x * 128 + wid * 32;

    bf16x8 af[2][8];
    #pragma unroll
    for (int mr = 0; mr < 2; ++mr)
        #pragma unroll
        for (int ks = 0; ks < 8; ++ks)
            af[mr][ks] = *(const bf16x8*)(a_bf + (size_t)(rowbase + mr * 16 + l15) * 512
                                               + ks * 64 + lk * 16);

    float s1v[2][4], s2v[2][4];
    #pragma unroll
    for (int mr = 0; mr < 2; ++mr)
        #pragma unroll
        for (int rg = 0; rg < 4; ++rg) { s1v[mr][rg] = 0.f; s2v[mr][rg] = 0.f; }

    #pragma unroll 1
    for (int ne = 0; ne < 8; ++ne) {
        f32x4 acc[2][2];
        #pragma unroll
        for (int mr = 0; mr < 2; ++mr)
            #pragma unroll
            for (int nt = 0; nt < 2; ++nt)
                acc[mr][nt] = (f32x4){0.f, 0.f, 0.f, 0.f};

        #pragma unroll
        for (int ks = 0; ks < 8; ++ks) {
            bf16x8 bfr[2];
            #pragma unroll
            for (int nt = 0; nt < 2; ++nt) {
                int n = ne * 32 + nt * 16 + l15;
                bfr[nt] = *(const bf16x8*)(Mb + (size_t)n * 512 + ks * 64 + lk * 16);
            }
            #pragma unroll
            for (int mr = 0; mr < 2; ++mr)
                #pragma unroll
                for (int nt = 0; nt < 2; ++nt)
                    acc[mr][nt] = __builtin_amdgcn_mfma_f32_16x16x32_bf16(
                        af[mr][ks], bfr[nt], acc[mr][nt], 0, 0, 0);
        }

        const float v0 = v[ne * 32 + l15];
        const float v1 = v[ne * 32 + 16 + l15];
        #pragma unroll
        for (int mr = 0; mr < 2; ++mr)
            #pragma unroll
            for (int rg = 0; rg < 4; ++rg) {
                const int row = rowbase + mr * 16 + lk * 4 + rg;
                float a0 = bf2f(*(const unsigned short*)(a_bf + (size_t)row * 512
                                                         + (ne * 32 + l15) * 2));
                float a1 = bf2f(*(const unsigned short*)(a_bf + (size_t)row * 512
                                                         + (ne * 32 + 16 + l15) * 2));
                s2v[mr][rg] += acc[mr][0][rg] * a0 + acc[mr][1][rg] * a1;
                s1v[mr][rg] += a0 * v0 + a1 * v1;
            }
    }

    float lossacc = 0.f;
    #pragma unroll
    for (int mr = 0; mr < 2; ++mr)
        #pragma unroll
        for (int rg = 0; rg < 4; ++rg) {
            float s1 = s1v[mr][rg], s2 = s2v[mr][rg];
            #pragma unroll
            for (int m = 1; m < 16; m <<= 1) {
                s1 += __shfl_xor(s1, m);
                s2 += __shfl_xor(s2, m);
            }
            if (l15 == 0) {
                const int row = rowbase + mr * 16 + lk * 4 + rg;
                lossacc += logf(NF + s1 + 0.5f * s2) - diag[row];
            }
        }
    #pragma unroll
    for (int m = 1; m < 64; m <<= 1) lossacc += __shfl_xor(lossacc, m);
    __shared__ float red[4];
    if (lane == 0) red[wid] = lossacc;
    __syncthreads();
    if (tid == 0) partial[blockIdx.x] = red[0] + red[1] + red[2] + red[3];
}

// ---------- kernel 4: final mean over 64 partials ----------
__global__ __launch_bounds__(64) void final_k(const float* __restrict__ partial,
                                              float* __restrict__ out) {
    const int t = threadIdx.x;
    float x = partial[t];
    #pragma unroll
    for (int m = 1; m < 64; m <<= 1) x += __shfl_xor(x, m);
    if (t == 0) out[0] = x / NF;
}

extern "C" void kernel_launch(void* const* d_in, const int* in_sizes, int n_in,
                              void* d_out, int out_size, void* d_ws, size_t ws_size,
                              hipStream_t stream) {
    const float* o1 = (const float*)d_in[0];
    const float* o2 = (const float*)d_in[1];

    unsigned char* w = (unsigned char*)d_ws;
    unsigned char*  a_bf = w;                                        // 4 MB
    unsigned char*  bt   = w + (size_t)4 * 1024 * 1024;              // 4 MB
    unsigned short* Mb   = (unsigned short*)(w + (size_t)8 * 1024 * 1024);      // 128 KB
    float*          vp   = (float*)(w + (size_t)8 * 1024 * 1024 + 131072);      // 256 KB
    float*          v    = vp + 256 * 256;                           // 1 KB
    float*          diag = v + 256;                                  // 32 KB
    float*          partial = diag + N;                              // 256 B

    conv_k <<<N / 32, 256, 0, stream>>>(o1, o2, a_bf, bt, vp, diag);
    mker2  <<<17, 512, 0, stream>>>(bt, vp, Mb, v);
    qf2    <<<64, 256, 0, stream>>>(a_bf, (const unsigned char*)Mb, v, diag, partial);
    final_k<<<1, 64, 0, stream>>>(partial, (float*)d_out);
}